// Round 4
// baseline (156.625 us; speedup 1.0000x reference)
//
#include <hip/hip_runtime.h>
#include <hip/hip_bf16.h>

typedef __attribute__((ext_vector_type(8))) __bf16 bf16x8;
typedef __attribute__((ext_vector_type(4))) float f32x4;

#define BATCH   1048576
#define DISTIL  128
#define CLASSES 64
#define NWAVES  2048          // 512 blocks x 4 waves (launch must match)
#define NTILES  (BATCH / 16)  // 65536
#define TPW     32            // tiles per wave: 65536 / 2048, exact

// D = W^T * z^T (transposed GEMM), 16x16x32 bf16 MFMA:
//   A frag: lane l holds W[kk*32+(l>>4)*8+j][n*16+(l&15)]       (persistent VGPRs)
//   B frag: lane l holds z[batch=l&15][kk*32+(l>>4)*8+j]        (reg double-buffer)
//   D frag: lane l, reg j -> out[batch=l&15][n*16+(l>>4)*4+j]   (contiguous dwordx4)
//
// Round-3 lesson: W fragments in LDS cost 16 KB of ds_read per tile per wave
// -> 224 B/cyc/CU demanded vs ~112 B/cyc LDS ceiling -> LDS-throughput-bound.
// Fix: W lives in 64 persistent VGPRs; zero LDS use. Occupancy drops to
// 8 waves/CU (launch_bounds(256,2), ~190 VGPR) which is ample for BW
// (memsets hit 86% HBM at ~3 waves/CU; prefetch keeps ~50 KB/CU in flight).

#define PREFETCH(buf, t) do {                                                  \
    const float* zr_ = z + ((t) * 16 + l15) * (long)DISTIL + lhi * 8;          \
    buf[0] = *(const f32x4*)(zr_);       buf[1] = *(const f32x4*)(zr_ + 4);    \
    buf[2] = *(const f32x4*)(zr_ + 32);  buf[3] = *(const f32x4*)(zr_ + 36);   \
    buf[4] = *(const f32x4*)(zr_ + 64);  buf[5] = *(const f32x4*)(zr_ + 68);   \
    buf[6] = *(const f32x4*)(zr_ + 96);  buf[7] = *(const f32x4*)(zr_ + 100);  \
} while (0)

#define COMPUTE(buf, t) do {                                                   \
    f32x4 acc0 = bias4[0], acc1 = bias4[1], acc2 = bias4[2], acc3 = bias4[3];  \
    _Pragma("unroll")                                                          \
    for (int kk = 0; kk < 4; ++kk) {                                           \
        f32x4 x0_ = buf[2*kk], x1_ = buf[2*kk+1];                              \
        bf16x8 a_;                                                             \
        _Pragma("unroll")                                                      \
        for (int j = 0; j < 4; ++j) { a_[j] = (__bf16)x0_[j]; a_[4+j] = (__bf16)x1_[j]; } \
        acc0 = __builtin_amdgcn_mfma_f32_16x16x32_bf16(bw[0][kk], a_, acc0, 0, 0, 0); \
        acc1 = __builtin_amdgcn_mfma_f32_16x16x32_bf16(bw[1][kk], a_, acc1, 0, 0, 0); \
        acc2 = __builtin_amdgcn_mfma_f32_16x16x32_bf16(bw[2][kk], a_, acc2, 0, 0, 0); \
        acc3 = __builtin_amdgcn_mfma_f32_16x16x32_bf16(bw[3][kk], a_, acc3, 0, 0, 0); \
    }                                                                          \
    float* orow_ = out + ((t) * 16 + l15) * (long)CLASSES + lhi * 4;           \
    *(f32x4*)(orow_)      = acc0;                                              \
    *(f32x4*)(orow_ + 16) = acc1;                                              \
    *(f32x4*)(orow_ + 32) = acc2;                                              \
    *(f32x4*)(orow_ + 48) = acc3;                                              \
} while (0)

__global__ __launch_bounds__(256, 2) void linclass_kernel(
    const float* __restrict__ z, const float* __restrict__ W,
    const float* __restrict__ bias, float* __restrict__ out)
{
    const int lane = threadIdx.x & 63;
    const int w    = threadIdx.x >> 6;   // wave id 0..3
    const int l15  = lane & 15;
    const int lhi  = lane >> 4;          // 0..3

    // ---- bias: lane l needs bias[n*16 + lhi*4 + j], j=0..3 ----
    f32x4 bias4[4];
#pragma unroll
    for (int n = 0; n < 4; ++n)
        bias4[n] = *(const f32x4*)(bias + n * 16 + lhi * 4);

    // ---- W fragments in persistent VGPRs (64 regs; W is 32 KB, L2-hot) ----
    // bw[n][kk][j] = W[kk*32 + lhi*8 + j][n*16 + l15]
    bf16x8 bw[4][4];
#pragma unroll
    for (int n = 0; n < 4; ++n) {
#pragma unroll
        for (int kk = 0; kk < 4; ++kk) {
            const int c     = n * 16 + l15;
            const int kbase = kk * 32 + lhi * 8;
#pragma unroll
            for (int j = 0; j < 8; ++j)
                bw[n][kk][j] = (__bf16)W[(kbase + j) * CLASSES + c];
        }
    }

    const long gwave = (long)blockIdx.x * 4 + w;   // 0..2047

    // ---- 32 tiles per wave, register double-buffered prefetch ----
    f32x4 bufA[8], bufB[8];
    PREFETCH(bufA, gwave);
#pragma unroll
    for (int i = 0; i < TPW; i += 2) {
        const long ta = gwave + (long)i * NWAVES;
        const long tb = ta + NWAVES;                 // i+1 <= 31, always valid
        PREFETCH(bufB, tb);
        COMPUTE(bufA, ta);
        if (i + 2 < TPW) PREFETCH(bufA, tb + NWAVES);
        COMPUTE(bufB, tb);
    }
}

extern "C" void kernel_launch(void* const* d_in, const int* in_sizes, int n_in,
                              void* d_out, int out_size, void* d_ws, size_t ws_size,
                              hipStream_t stream) {
    const float* z    = (const float*)d_in[0];   // [1048576, 128]
    const float* W    = (const float*)d_in[1];   // [128, 64]
    const float* bias = (const float*)d_in[2];   // [64]
    float* out        = (float*)d_out;           // [1048576, 64]

    dim3 grid(512), block(256);                  // 2048 waves == NWAVES
    linclass_kernel<<<grid, block, 0, stream>>>(z, W, bias, out);
}

// Round 5
// 151.720 us; speedup vs baseline: 1.0323x; 1.0323x over previous
//
#include <hip/hip_runtime.h>
#include <hip/hip_bf16.h>

typedef __attribute__((ext_vector_type(8))) __bf16 bf16x8;
typedef __attribute__((ext_vector_type(4))) float f32x4;

#define BATCH   1048576
#define DISTIL  128
#define CLASSES 64
#define NWAVES  4096          // 1024 blocks x 4 waves (launch must match)
#define NTILES  (BATCH / 16)  // 65536
#define TPW     16            // tiles per wave, exact

// D = W^T * z^T (transposed), 16x16x32 bf16 MFMA, W fragments in LDS (16 KB),
// z register-double-buffered. Key points this round:
//  - NO hand-asm waits: normal typed LDS reads; compiler emits counted lgkmcnt
//    and pipelines ds_read against cvt/MFMA (m97-style). Cross-tile CSE of the
//    (loop-invariant) LDS reads is blocked by a laundered zero index per tile.
//  - k-PERMUTATION: within an MFMA, k is a label; A and B just must agree.
//    phys_k(lhi,kk,j) = 32*kk + 16*(j>>2) + 4*lhi + (j&3). W is prepacked in
//    this order, so each z-load instruction reads row*512B + p*64 + lhi*16:
//    16 rows x one FULL 64-B sector -> sector-perfect, no half-sector requests.
//  - Fragment roles: A=W-frag -> D[class][batch]; lane l holds
//    out[batch=rowbase+(l&15)][class = n*16 + (l>>4)*4 + j] -> dwordx4 stores.

#define PREFETCH(buf, t) do {                                                  \
    const float* zr_ = z + ((t) * 16 + l15) * (long)DISTIL + lhi * 4;          \
    _Pragma("unroll")                                                          \
    for (int p = 0; p < 8; ++p) buf[p] = *(const f32x4*)(zr_ + p * 16);        \
} while (0)

#define COMPUTE(buf, t) do {                                                   \
    int foff_ = 0;                                                             \
    asm volatile("" : "+v"(foff_));    /* opaque 0: blocks cross-tile CSE */   \
    f32x4 acc0 = *(const f32x4*)(blds +  0 + lhi * 4 + foff_);                 \
    f32x4 acc1 = *(const f32x4*)(blds + 16 + lhi * 4 + foff_);                 \
    f32x4 acc2 = *(const f32x4*)(blds + 32 + lhi * 4 + foff_);                 \
    f32x4 acc3 = *(const f32x4*)(blds + 48 + lhi * 4 + foff_);                 \
    _Pragma("unroll")                                                          \
    for (int kk = 0; kk < 4; ++kk) {                                           \
        f32x4 x0_ = buf[2 * kk], x1_ = buf[2 * kk + 1];                        \
        bf16x8 a_;                                                             \
        _Pragma("unroll")                                                      \
        for (int j = 0; j < 4; ++j) {                                          \
            a_[j]     = (__bf16)x0_[j];                                        \
            a_[4 + j] = (__bf16)x1_[j];                                        \
        }                                                                      \
        bf16x8 b0_ = wf[ 0 + kk + foff_][lane];                                \
        bf16x8 b1_ = wf[ 4 + kk + foff_][lane];                                \
        bf16x8 b2_ = wf[ 8 + kk + foff_][lane];                                \
        bf16x8 b3_ = wf[12 + kk + foff_][lane];                                \
        acc0 = __builtin_amdgcn_mfma_f32_16x16x32_bf16(b0_, a_, acc0, 0, 0, 0);\
        acc1 = __builtin_amdgcn_mfma_f32_16x16x32_bf16(b1_, a_, acc1, 0, 0, 0);\
        acc2 = __builtin_amdgcn_mfma_f32_16x16x32_bf16(b2_, a_, acc2, 0, 0, 0);\
        acc3 = __builtin_amdgcn_mfma_f32_16x16x32_bf16(b3_, a_, acc3, 0, 0, 0);\
    }                                                                          \
    float* orow_ = out + ((t) * 16 + l15) * (long)CLASSES + lhi * 4;           \
    *(f32x4*)(orow_)      = acc0;                                              \
    *(f32x4*)(orow_ + 16) = acc1;                                              \
    *(f32x4*)(orow_ + 32) = acc2;                                              \
    *(f32x4*)(orow_ + 48) = acc3;                                              \
} while (0)

__global__ __launch_bounds__(256, 4) void linclass_kernel(
    const float* __restrict__ z, const float* __restrict__ W,
    const float* __restrict__ bias, float* __restrict__ out)
{
    const int lane = threadIdx.x & 63;
    const int w    = threadIdx.x >> 6;   // wave id 0..3
    const int l15  = lane & 15;
    const int lhi  = lane >> 4;          // 0..3

    // LDS: W fragments in permuted-k order + bias
    __shared__ __align__(16) bf16x8 wf[16][64];   // frag f = n*4+kk
    __shared__ __align__(16) float  blds[64];

    // prepack: wave w packs the 4 kk-frags for class group n == w
#pragma unroll
    for (int kk = 0; kk < 4; ++kk) {
        bf16x8 fr;
#pragma unroll
        for (int j = 0; j < 8; ++j) {
            const int phys = 32 * kk + ((j >> 2) << 4) + lhi * 4 + (j & 3);
            fr[j] = (__bf16)W[phys * CLASSES + w * 16 + l15];
        }
        wf[w * 4 + kk][lane] = fr;
    }
    if (threadIdx.x < 64) blds[threadIdx.x] = bias[threadIdx.x];
    __syncthreads();

    const long gwave = (long)blockIdx.x * 4 + w;   // 0..4095

    // 16 tiles per wave, register double-buffered z prefetch
    f32x4 bufA[8], bufB[8];
    PREFETCH(bufA, gwave);
#pragma unroll
    for (int i = 0; i < TPW; i += 2) {
        const long ta = gwave + (long)i * NWAVES;
        const long tb = ta + NWAVES;                 // i+1 <= 15, always valid
        PREFETCH(bufB, tb);
        COMPUTE(bufA, ta);
        if (i + 2 < TPW) PREFETCH(bufA, tb + NWAVES);
        COMPUTE(bufB, tb);
    }
}

extern "C" void kernel_launch(void* const* d_in, const int* in_sizes, int n_in,
                              void* d_out, int out_size, void* d_ws, size_t ws_size,
                              hipStream_t stream) {
    const float* z    = (const float*)d_in[0];   // [1048576, 128]
    const float* W    = (const float*)d_in[1];   // [128, 64]
    const float* bias = (const float*)d_in[2];   // [64]
    float* out        = (float*)d_out;           // [1048576, 64]

    dim3 grid(1024), block(256);                 // 4096 waves == NWAVES
    linclass_kernel<<<grid, block, 0, stream>>>(z, W, bias, out);
}